// Round 1
// baseline (3780.077 us; speedup 1.0000x reference)
//
#include <hip/hip_runtime.h>

// Problem constants (match reference)
#define B_DIM 16
#define U_DIM 1024
#define H_DIM 8
#define S_DIM 1024
#define C_DIM 128
#define SCALE 0.08838834764831845f  // 1/sqrt(128)

// ---------------------------------------------------------------------------
// Mask storage detection: the harness may pass the bool mask as uint8 (1B),
// int32 (4B, "integer -> const int*"), or float32. Values are only 0/1.
// Scan first 4096 dwords:
//   all dwords in {0,1}          -> int32 storage   (flag 0)
//   all dwords in {0,0x3F800000} -> float32 storage (flag 2)
//   otherwise                    -> byte storage    (flag 1)
// For byte storage with random 0/1 bytes, P(all 4096 dwords look like int32)
// ~ (1/8)^4096 ~ 0.
// ---------------------------------------------------------------------------
__global__ void detect_mask(const unsigned char* __restrict__ mask_raw, int* __restrict__ flag) {
  __shared__ int not01, notf;
  if (threadIdx.x == 0) { not01 = 0; notf = 0; }
  __syncthreads();
  const unsigned int* p = (const unsigned int*)mask_raw;
  int l01 = 0, lf = 0;
  for (int i = threadIdx.x; i < 4096; i += 256) {
    unsigned int v = p[i];
    if (v != 0u && v != 1u) l01 = 1;
    if (v != 0u && v != 0x3F800000u) lf = 1;
  }
  if (l01) atomicOr(&not01, 1);
  if (lf) atomicOr(&notf, 1);
  __syncthreads();
  if (threadIdx.x == 0) flag[0] = (!not01) ? 0 : ((!notf) ? 2 : 1);
}

// ---------------------------------------------------------------------------
// m[b,q] = sum_k mask[b,q,k]  (float). One wave per row, 4 rows per block.
// ---------------------------------------------------------------------------
__global__ __launch_bounds__(256) void mask_rowsum(const unsigned char* __restrict__ mask_raw,
                                                   const int* __restrict__ flag,
                                                   float* __restrict__ m_rows) {
  int row = blockIdx.x * 4 + (threadIdx.x >> 6);  // [0, B*S)
  int lane = threadIdx.x & 63;
  int mkind = flag[0];
  int sum = 0;
  if (mkind == 1) {
    const unsigned char* p = mask_raw + (size_t)row * S_DIM;
    for (int k = lane; k < S_DIM; k += 64) sum += (p[k] != 0);
  } else if (mkind == 0) {
    const int* p = (const int*)mask_raw + (size_t)row * S_DIM;
    for (int k = lane; k < S_DIM; k += 64) sum += (p[k] != 0);
  } else {
    const float* p = (const float*)mask_raw + (size_t)row * S_DIM;
    for (int k = lane; k < S_DIM; k += 64) sum += (p[k] != 0.f);
  }
#pragma unroll
  for (int off = 32; off > 0; off >>= 1) sum += __shfl_down(sum, off, 64);
  if (lane == 0) m_rows[row] = (float)sum;
}

// ---------------------------------------------------------------------------
// Batched GEMM: C[z][o][s] = sum_u A[o][u] * Bmat[z][u][s]
// A is (M x U_DIM) row-major fp32 shared across batch; B rows have stride
// S_DIM. 64x64 output tile per block, 256 threads, 4x4 micro-tile, K-tile 16.
// Used for both qkv projection (M=3072) and output projection (M=1024).
// ---------------------------------------------------------------------------
__global__ __launch_bounds__(256) void gemm64(const float* __restrict__ A,
                                              const float* __restrict__ Bmat,
                                              float* __restrict__ Cmat,
                                              long long strideBb, long long strideCb) {
  __shared__ float As[16][68];  // [k][o], pad to 68 (16B-aligned rows, no 4-way conflicts)
  __shared__ float Bs[16][68];  // [k][s]
  const float* Bb = Bmat + (size_t)blockIdx.z * (size_t)strideBb;
  float* Cb = Cmat + (size_t)blockIdx.z * (size_t)strideCb;
  const int tid = threadIdx.x;
  const int tx = tid & 15, ty = tid >> 4;
  const int o0 = blockIdx.y * 64, s0 = blockIdx.x * 64;
  const int aoRow = tid >> 2, aK = (tid & 3) * 4;  // A staging: float4 along k
  const int bK = tid >> 4, bS = (tid & 15) * 4;    // B staging: float4 along s (coalesced)
  float acc[4][4] = {{0.f}};
  for (int k0 = 0; k0 < U_DIM; k0 += 16) {
    float4 av = *(const float4*)(A + (size_t)(o0 + aoRow) * U_DIM + (k0 + aK));
    float4 bv = *(const float4*)(Bb + (size_t)(k0 + bK) * S_DIM + (s0 + bS));
    As[aK + 0][aoRow] = av.x;
    As[aK + 1][aoRow] = av.y;
    As[aK + 2][aoRow] = av.z;
    As[aK + 3][aoRow] = av.w;
    *(float4*)&Bs[bK][bS] = bv;
    __syncthreads();
#pragma unroll
    for (int kk = 0; kk < 16; ++kk) {
      float4 a4 = *(const float4*)&As[kk][ty * 4];
      float4 b4 = *(const float4*)&Bs[kk][tx * 4];
      const float ar[4] = {a4.x, a4.y, a4.z, a4.w};
      const float br[4] = {b4.x, b4.y, b4.z, b4.w};
#pragma unroll
      for (int i = 0; i < 4; ++i)
#pragma unroll
        for (int j = 0; j < 4; ++j) acc[i][j] += ar[i] * br[j];
    }
    __syncthreads();
  }
#pragma unroll
  for (int i = 0; i < 4; ++i) {
    float4 v = make_float4(acc[i][0], acc[i][1], acc[i][2], acc[i][3]);
    *(float4*)(Cb + (size_t)(o0 + ty * 4 + i) * S_DIM + (s0 + tx * 4)) = v;
  }
}

// ---------------------------------------------------------------------------
// Fused attention (no softmax -> no online rescaling needed):
//   P[q,k] = mask[b,q,k] ? max(S[q,k],0) * scale / m[b,q] : 0
//   Cc[b][h*128+c][q] = sum_k P[q,k] * V[c,k]
// One block per (q-tile of 32, h, batch). K-tiles of 32 streamed through LDS.
// ---------------------------------------------------------------------------
__global__ __launch_bounds__(256) void attn(const float* __restrict__ qkv,
                                            const unsigned char* __restrict__ mask_raw,
                                            const int* __restrict__ flag,
                                            const float* __restrict__ m_rows,
                                            float* __restrict__ Cc, int b0) {
  __shared__ float Qs[128][36];  // [c][q]
  __shared__ float Ks[128][36];  // [c][k]
  __shared__ float Vs[128][36];  // [c][k]
  __shared__ float Ps[32][36];   // [q][k]
  __shared__ float Ms[32][36];   // [q][k] 0/1
  __shared__ float invm[32];

  const int tid = threadIdx.x;
  const int qt = blockIdx.x, h = blockIdx.y, bl = blockIdx.z;
  const int b = b0 + bl;
  const int q0 = qt * 32;
  const float* qb = qkv + ((size_t)bl * 3 * U_DIM + (size_t)h * C_DIM) * S_DIM;
  const float* kb = qb + (size_t)U_DIM * S_DIM;
  const float* vb = qb + (size_t)2 * U_DIM * S_DIM;

  // stage Q tile (128 c x 32 q)
  for (int idx = tid; idx < 128 * 8; idx += 256) {
    int c = idx >> 3, q4 = (idx & 7) * 4;
    *(float4*)&Qs[c][q4] = *(const float4*)(qb + (size_t)c * S_DIM + q0 + q4);
  }
  if (tid < 32) {
    float mm = m_rows[(size_t)b * S_DIM + q0 + tid];
    invm[tid] = (mm > 0.f) ? (SCALE / mm) : 0.f;  // m==0 => whole row masked anyway
  }
  const int mkind = flag[0];

  const int sqq = tid & 31, sg = tid >> 5;             // scores: (q, 4k group)
  const int pq4 = (tid & 7) * 4, pc4 = (tid >> 3) * 4; // PV: 4q x 4c micro-tile
  const int mq = tid >> 3, mk4 = (tid & 7) * 4;        // mask staging

  float acc[4][4] = {{0.f}};  // [c_off][q_off]

  for (int kt = 0; kt < S_DIM / 32; ++kt) {
    const int k0 = kt * 32;
    // stage K, V tiles
    for (int idx = tid; idx < 128 * 8; idx += 256) {
      int c = idx >> 3, k4 = (idx & 7) * 4;
      *(float4*)&Ks[c][k4] = *(const float4*)(kb + (size_t)c * S_DIM + k0 + k4);
      *(float4*)&Vs[c][k4] = *(const float4*)(vb + (size_t)c * S_DIM + k0 + k4);
    }
    // stage mask tile (coalesced along k)
    {
      float mv0, mv1, mv2, mv3;
      if (mkind == 1) {
        const unsigned char* mp = mask_raw + ((size_t)b * S_DIM + q0 + mq) * S_DIM + k0 + mk4;
        uchar4 v = *(const uchar4*)mp;
        mv0 = v.x ? 1.f : 0.f; mv1 = v.y ? 1.f : 0.f; mv2 = v.z ? 1.f : 0.f; mv3 = v.w ? 1.f : 0.f;
      } else if (mkind == 0) {
        const int* mp = (const int*)mask_raw + ((size_t)b * S_DIM + q0 + mq) * S_DIM + k0 + mk4;
        int4 v = *(const int4*)mp;
        mv0 = v.x ? 1.f : 0.f; mv1 = v.y ? 1.f : 0.f; mv2 = v.z ? 1.f : 0.f; mv3 = v.w ? 1.f : 0.f;
      } else {
        const float* mp = (const float*)mask_raw + ((size_t)b * S_DIM + q0 + mq) * S_DIM + k0 + mk4;
        float4 v = *(const float4*)mp;
        mv0 = (v.x != 0.f) ? 1.f : 0.f; mv1 = (v.y != 0.f) ? 1.f : 0.f;
        mv2 = (v.z != 0.f) ? 1.f : 0.f; mv3 = (v.w != 0.f) ? 1.f : 0.f;
      }
      Ms[mq][mk4 + 0] = mv0; Ms[mq][mk4 + 1] = mv1; Ms[mq][mk4 + 2] = mv2; Ms[mq][mk4 + 3] = mv3;
    }
    __syncthreads();

    // scores: each thread -> score(sqq, sg*4 + 0..3), 128-deep dot
    float sc0 = 0.f, sc1 = 0.f, sc2 = 0.f, sc3 = 0.f;
#pragma unroll 4
    for (int c = 0; c < 128; ++c) {
      float qv = Qs[c][sqq];
      float4 kv = *(const float4*)&Ks[c][sg * 4];
      sc0 += qv * kv.x; sc1 += qv * kv.y; sc2 += qv * kv.z; sc3 += qv * kv.w;
    }
    {
      float iv = invm[sqq];
      Ps[sqq][sg * 4 + 0] = fmaxf(sc0, 0.f) * iv * Ms[sqq][sg * 4 + 0];
      Ps[sqq][sg * 4 + 1] = fmaxf(sc1, 0.f) * iv * Ms[sqq][sg * 4 + 1];
      Ps[sqq][sg * 4 + 2] = fmaxf(sc2, 0.f) * iv * Ms[sqq][sg * 4 + 2];
      Ps[sqq][sg * 4 + 3] = fmaxf(sc3, 0.f) * iv * Ms[sqq][sg * 4 + 3];
    }
    __syncthreads();

    // PV: acc[i][j] += sum_k Vs[pc4+i][k] * Ps[pq4+j][k]
#pragma unroll
    for (int kq = 0; kq < 8; ++kq) {
      float4 vv[4], pp[4];
#pragma unroll
      for (int i = 0; i < 4; ++i) vv[i] = *(const float4*)&Vs[pc4 + i][kq * 4];
#pragma unroll
      for (int j = 0; j < 4; ++j) pp[j] = *(const float4*)&Ps[pq4 + j][kq * 4];
#pragma unroll
      for (int i = 0; i < 4; ++i)
#pragma unroll
        for (int j = 0; j < 4; ++j)
          acc[i][j] += vv[i].x * pp[j].x + vv[i].y * pp[j].y + vv[i].z * pp[j].z + vv[i].w * pp[j].w;
    }
    __syncthreads();
  }

  // write Cc[bl][h*128 + c][q0 + q]
  float* cb = Cc + ((size_t)bl * U_DIM + (size_t)h * C_DIM) * S_DIM;
#pragma unroll
  for (int i = 0; i < 4; ++i) {
    float4 v = make_float4(acc[i][0], acc[i][1], acc[i][2], acc[i][3]);
    *(float4*)(cb + (size_t)(pc4 + i) * S_DIM + q0 + pq4) = v;
  }
}

// ---------------------------------------------------------------------------
extern "C" void kernel_launch(void* const* d_in, const int* in_sizes, int n_in,
                              void* d_out, int out_size, void* d_ws, size_t ws_size,
                              hipStream_t stream) {
  const float* x = (const float*)d_in[0];
  const unsigned char* mask_raw = (const unsigned char*)d_in[1];
  const float* w_qkv = (const float*)d_in[2];
  const float* w_out = (const float*)d_in[3];
  float* out = (float*)d_out;

  char* ws = (char*)d_ws;
  int* flag = (int*)ws;                         // 256 B reserved
  float* m_rows = (float*)(ws + 256);           // B*S floats = 64 KB
  char* heap = ws + 256 + (size_t)B_DIM * S_DIM * sizeof(float);

  // per-batch scratch: qkv (3U x S f32) + Cc (U x S f32) = 16.8 MB
  const size_t qkv_bytes_pb = (size_t)(3 * U_DIM) * S_DIM * sizeof(float);
  const size_t cc_bytes_pb = (size_t)U_DIM * S_DIM * sizeof(float);
  const size_t per_batch = qkv_bytes_pb + cc_bytes_pb;
  size_t avail = (ws_size > 256 + 65536) ? (ws_size - 256 - 65536) : 0;
  int nb = (int)(avail / per_batch);
  if (nb < 1) nb = 1;
  if (nb > B_DIM) nb = B_DIM;

  float* qkv_ws = (float*)heap;
  float* cc_ws = (float*)(heap + (size_t)nb * qkv_bytes_pb);

  detect_mask<<<1, 256, 0, stream>>>(mask_raw, flag);
  mask_rowsum<<<(B_DIM * S_DIM) / 4, 256, 0, stream>>>(mask_raw, flag, m_rows);

  for (int b0 = 0; b0 < B_DIM; b0 += nb) {
    int cnt = (B_DIM - b0 < nb) ? (B_DIM - b0) : nb;
    // qkv[b][o][s] = sum_u w_qkv[o][u] * x[b][u][s]
    gemm64<<<dim3(S_DIM / 64, (3 * U_DIM) / 64, cnt), 256, 0, stream>>>(
        w_qkv, x + (size_t)b0 * U_DIM * S_DIM, qkv_ws,
        (long long)U_DIM * S_DIM, (long long)(3 * U_DIM) * S_DIM);
    // attention
    attn<<<dim3(S_DIM / 32, H_DIM, cnt), 256, 0, stream>>>(
        qkv_ws, mask_raw, flag, m_rows, cc_ws, b0);
    // out[b][o][s] = sum_u w_out[o][u] * Cc[b][u][s]
    gemm64<<<dim3(S_DIM / 64, U_DIM / 64, cnt), 256, 0, stream>>>(
        w_out, cc_ws, out + (size_t)b0 * U_DIM * S_DIM,
        (long long)U_DIM * S_DIM, (long long)U_DIM * S_DIM);
  }
}

// Round 2
// 514.003 us; speedup vs baseline: 7.3542x; 7.3542x over previous
//
#include <hip/hip_runtime.h>

#define B_DIM 16
#define U_DIM 1024
#define H_DIM 8
#define S_DIM 1024
#define C_DIM 128
#define KD 1024  // K depth of both projection GEMMs
#define SCALE 0.08838834764831845f  // 1/sqrt(128)

typedef __attribute__((ext_vector_type(8))) short s16x8;
typedef __attribute__((ext_vector_type(4))) float f32x4;

__device__ __forceinline__ void gll16(const void* g, void* l) {
  __builtin_amdgcn_global_load_lds(
      (const __attribute__((address_space(1))) unsigned int*)g,
      (__attribute__((address_space(3))) unsigned int*)l, 16, 0, 0);
}
__device__ __forceinline__ unsigned short f2bf(float f) {
  unsigned u = __float_as_uint(f);
  u += 0x7FFF + ((u >> 16) & 1u);
  return (unsigned short)(u >> 16);
}
#define MFMA16(a, b, c) __builtin_amdgcn_mfma_f32_16x16x32_bf16(a, b, c, 0, 0, 0)

// ---------------------------------------------------------------------------
// Mask storage detection (bool may arrive as u8 / i32 / f32). See R1 notes.
// ---------------------------------------------------------------------------
__global__ void detect_mask(const unsigned char* __restrict__ mask_raw, int* __restrict__ flag) {
  __shared__ int not01, notf;
  if (threadIdx.x == 0) { not01 = 0; notf = 0; }
  __syncthreads();
  const unsigned int* p = (const unsigned int*)mask_raw;
  int l01 = 0, lf = 0;
  for (int i = threadIdx.x; i < 4096; i += 256) {
    unsigned int v = p[i];
    if (v != 0u && v != 1u) l01 = 1;
    if (v != 0u && v != 0x3F800000u) lf = 1;
  }
  if (l01) atomicOr(&not01, 1);
  if (lf) atomicOr(&notf, 1);
  __syncthreads();
  if (threadIdx.x == 0) flag[0] = (!not01) ? 0 : ((!notf) ? 2 : 1);
}

// invm[b,q] = (rowsum>0) ? SCALE/rowsum : 0
__global__ __launch_bounds__(256) void mask_invm(const unsigned char* __restrict__ mask_raw,
                                                 const int* __restrict__ flag,
                                                 float* __restrict__ invm) {
  int row = blockIdx.x * 4 + (threadIdx.x >> 6);
  int lane = threadIdx.x & 63;
  int mkind = flag[0];
  int sum = 0;
  if (mkind == 1) {
    const unsigned char* p = mask_raw + (size_t)row * S_DIM;
    for (int k = lane; k < S_DIM; k += 64) sum += (p[k] != 0);
  } else if (mkind == 0) {
    const int* p = (const int*)mask_raw + (size_t)row * S_DIM;
    for (int k = lane; k < S_DIM; k += 64) sum += (p[k] != 0);
  } else {
    const float* p = (const float*)mask_raw + (size_t)row * S_DIM;
    for (int k = lane; k < S_DIM; k += 64) sum += (p[k] != 0.f);
  }
#pragma unroll
  for (int off = 32; off > 0; off >>= 1) sum += __shfl_down(sum, off, 64);
  if (lane == 0) invm[row] = (sum > 0) ? (SCALE / (float)sum) : 0.f;
}

// fp32 -> bf16 elementwise (weights)
__global__ __launch_bounds__(256) void cvt_bf16(const float* __restrict__ in,
                                                unsigned short* __restrict__ out, int n) {
  int i = (blockIdx.x * 256 + threadIdx.x) * 4;
  if (i < n) {
    float4 v = *(const float4*)(in + i);
    ushort4 o;
    o.x = f2bf(v.x); o.y = f2bf(v.y); o.z = f2bf(v.z); o.w = f2bf(v.w);
    *(ushort4*)(out + i) = o;
  }
}

// x[b][u][s] f32 -> xT[b][s][u] bf16   (32x32 tiles)
__global__ __launch_bounds__(256) void transpose_x(const float* __restrict__ x,
                                                   unsigned short* __restrict__ xT) {
  __shared__ float T[32][33];
  const int t = threadIdx.x, r = t >> 3, c4 = (t & 7) * 4;
  const int s0 = blockIdx.x * 32, u0 = blockIdx.y * 32;
  const size_t base = (size_t)blockIdx.z * U_DIM * S_DIM;
  float4 v = *(const float4*)(x + base + (size_t)(u0 + r) * S_DIM + s0 + c4);
  T[r][c4 + 0] = v.x; T[r][c4 + 1] = v.y; T[r][c4 + 2] = v.z; T[r][c4 + 3] = v.w;
  __syncthreads();
  ushort4 o;
  o.x = f2bf(T[c4 + 0][r]); o.y = f2bf(T[c4 + 1][r]);
  o.z = f2bf(T[c4 + 2][r]); o.w = f2bf(T[c4 + 3][r]);
  *(ushort4*)(xT + base + (size_t)(s0 + r) * U_DIM + u0 + c4) = o;
}

// qkvT[b][k][2048+c] bf16 -> VT[b][c][k] bf16  (32x32 tiles)
__global__ __launch_bounds__(256) void transpose_v(const unsigned short* __restrict__ qkvT,
                                                   unsigned short* __restrict__ VT) {
  __shared__ unsigned short T[32][34];
  const int t = threadIdx.x, r = t >> 3, c4 = (t & 7) * 4;
  const int k0 = blockIdx.x * 32, c0 = blockIdx.y * 32;
  const unsigned short* qb = qkvT + (size_t)blockIdx.z * S_DIM * (3 * U_DIM);
  ushort4 v = *(const ushort4*)(qb + (size_t)(k0 + r) * (3 * U_DIM) + 2 * U_DIM + c0 + c4);
  T[r][c4 + 0] = v.x; T[r][c4 + 1] = v.y; T[r][c4 + 2] = v.z; T[r][c4 + 3] = v.w;
  __syncthreads();
  ushort4 o;
  o.x = T[c4 + 0][r]; o.y = T[c4 + 1][r]; o.z = T[c4 + 2][r]; o.w = T[c4 + 3][r];
  *(ushort4*)(VT + (size_t)blockIdx.z * U_DIM * S_DIM + (size_t)(c0 + r) * S_DIM + k0 + c4) = o;
}

// ---------------------------------------------------------------------------
// bf16 MFMA GEMM (m97 structure + XOR-swizzled LDS chunks):
//   D[m][n] = sum_k A[m][k] * B[n][k];  A,B row-major with K=1024 contiguous.
//   128x128 block tile, 4 waves in 2x2, 64x64 per wave, BK=32.
// ---------------------------------------------------------------------------
template <typename OUT>
__global__ __launch_bounds__(256) void gemm_tt(const unsigned short* __restrict__ A,
                                               const unsigned short* __restrict__ Bm,
                                               OUT* __restrict__ D,
                                               long long sAb, long long sBb, long long sDb,
                                               int N) {
  __shared__ unsigned short sA[128 * 32];
  __shared__ unsigned short sB[128 * 32];
  const int tid = threadIdx.x, wave = tid >> 6, lane = tid & 63;
  const int l15 = lane & 15, quad = lane >> 4;
  const int m0 = blockIdx.y * 128, n0 = blockIdx.x * 128;
  A += (size_t)blockIdx.z * sAb;
  Bm += (size_t)blockIdx.z * sBb;
  D += (size_t)blockIdx.z * sDb;
  const int wm = (wave >> 1) * 64, wn = (wave & 1) * 64;
  f32x4 acc[4][4] = {};

  for (int k0 = 0; k0 < KD; k0 += 32) {
#pragma unroll
    for (int t = 0; t < 2; ++t) {
      int p = wave * 128 + t * 64 + lane;
      int row = p >> 2, kc = (p & 3) ^ (row & 3);  // XOR swizzle: b128 reads land 2-way max
      gll16(A + (size_t)(m0 + row) * KD + k0 + kc * 8, &sA[(wave * 128 + t * 64) * 8]);
    }
#pragma unroll
    for (int t = 0; t < 2; ++t) {
      int p = wave * 128 + t * 64 + lane;
      int row = p >> 2, kc = (p & 3) ^ (row & 3);
      gll16(Bm + (size_t)(n0 + row) * KD + k0 + kc * 8, &sB[(wave * 128 + t * 64) * 8]);
    }
    __syncthreads();
    s16x8 af[4], bf[4];
#pragma unroll
    for (int i = 0; i < 4; ++i) {
      int row = wm + i * 16 + l15;
      af[i] = *(const s16x8*)&sA[row * 32 + (quad ^ (row & 3)) * 8];
    }
#pragma unroll
    for (int j = 0; j < 4; ++j) {
      int row = wn + j * 16 + l15;
      bf[j] = *(const s16x8*)&sB[row * 32 + (quad ^ (row & 3)) * 8];
    }
#pragma unroll
    for (int i = 0; i < 4; ++i)
#pragma unroll
      for (int j = 0; j < 4; ++j) acc[i][j] = MFMA16(af[i], bf[j], acc[i][j]);
    __syncthreads();
  }
#pragma unroll
  for (int i = 0; i < 4; ++i)
#pragma unroll
    for (int j = 0; j < 4; ++j) {
      f32x4 v = acc[i][j];
#pragma unroll
      for (int r = 0; r < 4; ++r) {
        int m = m0 + wm + i * 16 + quad * 4 + r;  // C/D: row=(lane>>4)*4+reg
        int n = n0 + wn + j * 16 + l15;           //      col=lane&15
        if constexpr (sizeof(OUT) == 2) D[(size_t)m * N + n] = f2bf(v[r]);
        else D[(size_t)m * N + n] = v[r];
      }
    }
}

// ---------------------------------------------------------------------------
// Fused masked-relu attention, bf16 MFMA.
// Block = (q-tile 64, head, batch). K-tiles of 64.
//   scores D[q][k] = Q.K (K-dim=c=128) -> P = mask*relu*invm -> LDS -> PV D[q][c]
// ---------------------------------------------------------------------------
__global__ __launch_bounds__(256, 2) void attn_mfma(const unsigned short* __restrict__ qkvT,
                                                    const unsigned short* __restrict__ VT,
                                                    const unsigned char* __restrict__ mask_raw,
                                                    const int* __restrict__ flag,
                                                    const float* __restrict__ invm,
                                                    unsigned short* __restrict__ CcT, int b0) {
  __shared__ unsigned short Qs[64 * 128];  // [q][c] swizzled
  __shared__ unsigned short Ks[64 * 128];  // [k][c] swizzled
  __shared__ unsigned short Vs[128 * 64];  // [c][k] swizzled
  __shared__ unsigned short Ps[64 * 64];   // [q][k] swizzled
  __shared__ float invs[64];

  const int tid = threadIdx.x, wave = tid >> 6, lane = tid & 63;
  const int l15 = lane & 15, quad = lane >> 4;
  const int q0 = blockIdx.x * 64, h = blockIdx.y, z = blockIdx.z, b = b0 + z;
  const unsigned short* qB = qkvT + (size_t)z * S_DIM * (3 * U_DIM);
  const unsigned short* Vb = VT + (size_t)z * U_DIM * S_DIM + (size_t)h * C_DIM * S_DIM;
  const int mkind = flag[0];

  // stage Q tile (64 rows x 16 chunks, chunk ^= row&7)
#pragma unroll
  for (int t = 0; t < 4; ++t) {
    int p = wave * 256 + t * 64 + lane;
    int row = p >> 4, c = (p & 15) ^ (row & 7);
    gll16(qB + (size_t)(q0 + row) * (3 * U_DIM) + h * C_DIM + c * 8,
          &Qs[(wave * 256 + t * 64) * 8]);
  }
  if (tid < 64) invs[tid] = invm[(size_t)b * S_DIM + q0 + tid];
  __syncthreads();

  // Q fragments and invm held in registers for the whole block
  s16x8 qf[4][4];
#pragma unroll
  for (int i = 0; i < 4; ++i)
#pragma unroll
    for (int kk = 0; kk < 4; ++kk) {
      int row = i * 16 + l15;
      qf[i][kk] = *(const s16x8*)&Qs[row * 128 + ((kk * 4 + quad) ^ (row & 7)) * 8];
    }
  float invf[4][4];
#pragma unroll
  for (int i = 0; i < 4; ++i)
#pragma unroll
    for (int r = 0; r < 4; ++r) invf[i][r] = invs[i * 16 + quad * 4 + r];

  f32x4 pacc[4][2] = {};

  for (int kt = 0; kt < S_DIM / 64; ++kt) {
    const int k0t = kt * 64;
    __syncthreads();  // prev PV done before overwriting Ks/Vs
    // stage K tile
#pragma unroll
    for (int t = 0; t < 4; ++t) {
      int p = wave * 256 + t * 64 + lane;
      int row = p >> 4, c = (p & 15) ^ (row & 7);
      gll16(qB + (size_t)(k0t + row) * (3 * U_DIM) + U_DIM + h * C_DIM + c * 8,
            &Ks[(wave * 256 + t * 64) * 8]);
    }
    // stage V tile ([c][k], 128 rows x 8 chunks)
#pragma unroll
    for (int t = 0; t < 4; ++t) {
      int p = wave * 256 + t * 64 + lane;
      int row = p >> 3, kc = (p & 7) ^ (row & 7);
      gll16(Vb + (size_t)row * S_DIM + k0t + kc * 8, &Vs[(wave * 256 + t * 64) * 8]);
    }
    // mask loads (overlap with staging; consumed after barrier)
    float msel[4][4];
    {
      const int kg = k0t + wave * 16 + l15;
      if (mkind == 1) {
        const unsigned char* mp = mask_raw + ((size_t)b << 20);
#pragma unroll
        for (int i = 0; i < 4; ++i)
#pragma unroll
          for (int r = 0; r < 4; ++r) {
            int q = q0 + i * 16 + quad * 4 + r;
            msel[i][r] = mp[((size_t)q << 10) + kg] ? 1.f : 0.f;
          }
      } else if (mkind == 0) {
        const int* mp = (const int*)mask_raw + ((size_t)b << 20);
#pragma unroll
        for (int i = 0; i < 4; ++i)
#pragma unroll
          for (int r = 0; r < 4; ++r) {
            int q = q0 + i * 16 + quad * 4 + r;
            msel[i][r] = mp[((size_t)q << 10) + kg] ? 1.f : 0.f;
          }
      } else {
        const float* mp = (const float*)mask_raw + ((size_t)b << 20);
#pragma unroll
        for (int i = 0; i < 4; ++i)
#pragma unroll
          for (int r = 0; r < 4; ++r) {
            int q = q0 + i * 16 + quad * 4 + r;
            msel[i][r] = (mp[((size_t)q << 10) + kg] != 0.f) ? 1.f : 0.f;
          }
      }
    }
    __syncthreads();  // K/V tiles ready

    // scores: wave handles k-cols [wave*16, wave*16+16), all 64 q rows
    f32x4 sacc[4] = {};
#pragma unroll
    for (int kk = 0; kk < 4; ++kk) {
      int row = wave * 16 + l15;
      s16x8 bk = *(const s16x8*)&Ks[row * 128 + ((kk * 4 + quad) ^ (row & 7)) * 8];
#pragma unroll
      for (int i = 0; i < 4; ++i) sacc[i] = MFMA16(qf[i][kk], bk, sacc[i]);
    }
    // P = mask * relu(s) * scale/m  -> bf16 -> LDS (swizzled [q][k])
#pragma unroll
    for (int i = 0; i < 4; ++i)
#pragma unroll
      for (int r = 0; r < 4; ++r) {
        int q = i * 16 + quad * 4 + r;
        int kl = wave * 16 + l15;
        float p = fmaxf(sacc[i][r], 0.f) * invf[i][r] * msel[i][r];
        Ps[q * 64 + (((kl >> 3) ^ (q & 7))) * 8 + (kl & 7)] = f2bf(p);
      }
    __syncthreads();  // P ready

    // PV: wave handles c-cols [wave*32, wave*32+32)
#pragma unroll
    for (int ks = 0; ks < 2; ++ks) {
      s16x8 pf[4], vf[2];
#pragma unroll
      for (int i = 0; i < 4; ++i) {
        int row = i * 16 + l15;
        pf[i] = *(const s16x8*)&Ps[row * 64 + ((ks * 4 + quad) ^ (row & 7)) * 8];
      }
#pragma unroll
      for (int j = 0; j < 2; ++j) {
        int row = wave * 32 + j * 16 + l15;
        vf[j] = *(const s16x8*)&Vs[row * 64 + ((ks * 4 + quad) ^ (row & 7)) * 8];
      }
#pragma unroll
      for (int i = 0; i < 4; ++i)
#pragma unroll
        for (int j = 0; j < 2; ++j) pacc[i][j] = MFMA16(pf[i], vf[j], pacc[i][j]);
    }
  }

  // epilogue: CcT[b][q][h*128+c] bf16
  unsigned short* cb = CcT + (size_t)z * S_DIM * U_DIM;
#pragma unroll
  for (int i = 0; i < 4; ++i)
#pragma unroll
    for (int j = 0; j < 2; ++j) {
      f32x4 v = pacc[i][j];
#pragma unroll
      for (int r = 0; r < 4; ++r) {
        int q = q0 + i * 16 + quad * 4 + r;
        int c = h * C_DIM + wave * 32 + j * 16 + l15;
        cb[(size_t)q * U_DIM + c] = f2bf(v[r]);
      }
    }
}

// ---------------------------------------------------------------------------
extern "C" void kernel_launch(void* const* d_in, const int* in_sizes, int n_in,
                              void* d_out, int out_size, void* d_ws, size_t ws_size,
                              hipStream_t stream) {
  const float* x = (const float*)d_in[0];
  const unsigned char* mask_raw = (const unsigned char*)d_in[1];
  const float* w_qkv = (const float*)d_in[2];
  const float* w_out = (const float*)d_in[3];
  float* out = (float*)d_out;

  char* ws = (char*)d_ws;
  int* flag = (int*)ws;                                        // 256 B
  float* invm = (float*)(ws + 256);                            // 64 KB
  unsigned short* wqkv_bf = (unsigned short*)(ws + 256 + 65536);           // 6 MB
  unsigned short* wout_bf = (unsigned short*)((char*)wqkv_bf + (size_t)3 * U_DIM * U_DIM * 2);
  char* heap = (char*)wout_bf + (size_t)U_DIM * U_DIM * 2;

  const size_t xT_pb = (size_t)U_DIM * S_DIM * 2;
  const size_t qkvT_pb = (size_t)3 * U_DIM * S_DIM * 2;
  const size_t vT_pb = (size_t)U_DIM * S_DIM * 2;
  const size_t ccT_pb = (size_t)U_DIM * S_DIM * 2;
  const size_t per_batch = xT_pb + qkvT_pb + vT_pb + ccT_pb;  // 12.58 MB
  const size_t fixed = (size_t)(heap - ws);
  int nb = (ws_size > fixed) ? (int)((ws_size - fixed) / per_batch) : 1;
  if (nb < 1) nb = 1;
  if (nb > B_DIM) nb = B_DIM;

  unsigned short* xT = (unsigned short*)heap;
  unsigned short* qkvT = (unsigned short*)(heap + (size_t)nb * xT_pb);
  unsigned short* VT = (unsigned short*)(heap + (size_t)nb * (xT_pb + qkvT_pb));
  unsigned short* CcT = (unsigned short*)(heap + (size_t)nb * (xT_pb + qkvT_pb + vT_pb));

  detect_mask<<<1, 256, 0, stream>>>(mask_raw, flag);
  mask_invm<<<(B_DIM * S_DIM) / 4, 256, 0, stream>>>(mask_raw, flag, invm);
  cvt_bf16<<<(3 * U_DIM * U_DIM) / 1024, 256, 0, stream>>>(w_qkv, wqkv_bf, 3 * U_DIM * U_DIM);
  cvt_bf16<<<(U_DIM * U_DIM) / 1024, 256, 0, stream>>>(w_out, wout_bf, U_DIM * U_DIM);

  for (int b0 = 0; b0 < B_DIM; b0 += nb) {
    int cnt = (B_DIM - b0 < nb) ? (B_DIM - b0) : nb;
    transpose_x<<<dim3(S_DIM / 32, U_DIM / 32, cnt), 256, 0, stream>>>(
        x + (size_t)b0 * U_DIM * S_DIM, xT);
    // qkvT[s][o] = sum_u xT[s][u] * w_qkv[o][u]
    gemm_tt<unsigned short><<<dim3(3 * U_DIM / 128, S_DIM / 128, cnt), 256, 0, stream>>>(
        xT, wqkv_bf, qkvT, (long long)U_DIM * S_DIM, 0LL, (long long)3 * U_DIM * S_DIM, 3 * U_DIM);
    transpose_v<<<dim3(S_DIM / 32, U_DIM / 32, cnt), 256, 0, stream>>>(qkvT, VT);
    attn_mfma<<<dim3(S_DIM / 64, H_DIM, cnt), 256, 0, stream>>>(
        qkvT, VT, mask_raw, flag, invm, CcT, b0);
    // out[o][s] = sum_u w_out[o][u] * CcT[s][u]
    gemm_tt<float><<<dim3(S_DIM / 128, U_DIM / 128, cnt), 256, 0, stream>>>(
        wout_bf, CcT, out + (size_t)b0 * U_DIM * S_DIM, 0LL,
        (long long)U_DIM * S_DIM, (long long)U_DIM * S_DIM, S_DIM);
  }
}